// Round 3
// baseline (110.042 us; speedup 1.0000x reference)
//
#include <hip/hip_runtime.h>
#include <math.h>

#define NB 8
#define NN 1024
#define NI 64
#define NO 32
#define NH 4
#define NEGINF (-1e30f)

typedef _Float16 half8 __attribute__((ext_vector_type(8)));
typedef _Float16 half4v __attribute__((ext_vector_type(4)));
typedef float floatx4 __attribute__((ext_vector_type(4)));

// ---------------- Kernel 0: pack adj int32 -> byte ----------------
__global__ __launch_bounds__(256) void k_pack(const int* __restrict__ adj,
                                              unsigned char* __restrict__ adjb) {
    const int i = blockIdx.x * 256 + threadIdx.x;   // 262144 int4 groups
    const int4 v = ((const int4*)adj)[i];
    unsigned int p = (v.x ? 1u : 0u) | ((v.y ? 1u : 0u) << 8) |
                     ((v.z ? 1u : 0u) << 16) | ((v.w ? 1u : 0u) << 24);
    ((unsigned int*)adjb)[i] = p;
}

// ---------------- Kernel 1: projection + scores ----------------
__global__ __launch_bounds__(256) void k_proj(
    const float* __restrict__ x, const float* __restrict__ beta,
    const float* __restrict__ weight, const float* __restrict__ attn_src,
    const float* __restrict__ attn_dst, const float* __restrict__ bias,
    const float* __restrict__ prior,
    _Float16* __restrict__ projT,   // [B,H,O,N] fp16
    float* __restrict__ src_s, float* __restrict__ dst_s, float* __restrict__ gp)
{
    __shared__ __align__(16) float xs[32 * 64];       // [n][i]
    __shared__ __align__(16) float ws[4 * 64 * 36];   // [h][i][o pad 36]
    const int t = threadIdx.x;
    const int ntile = blockIdx.x, b = blockIdx.y;
    const int n0b = ntile * 32;
    {
        const float4* xsrc = (const float4*)(x + ((size_t)b * NN + n0b) * NI);
        float4* xd = (float4*)xs;
        xd[t] = xsrc[t];
        xd[t + 256] = xsrc[t + 256];
    }
    #pragma unroll
    for (int k = 0; k < 8; ++k) {
        int e = t + k * 256;
        int h = e >> 9, rem = e & 511, i = rem >> 3, o4 = rem & 7;
        float4 wv = *(const float4*)(weight + (h * NI + i) * NO + o4 * 4);
        *(float4*)&ws[h * 2304 + i * 36 + o4 * 4] = wv;
    }
    __syncthreads();

    const int o4 = t & 7, h = (t >> 3) & 3, ng = t >> 5;
    const int o0 = o4 * 4, nl0 = ng * 4;
    float acc[4][4];
    #pragma unroll
    for (int kn = 0; kn < 4; ++kn)
        #pragma unroll
        for (int oo = 0; oo < 4; ++oo) acc[kn][oo] = 0.f;

    #pragma unroll 4
    for (int i = 0; i < NI; ++i) {
        const float4 wv = *(const float4*)&ws[h * 2304 + i * 36 + o0];
        #pragma unroll
        for (int kn = 0; kn < 4; ++kn) {
            const float xv = xs[(nl0 + kn) * 64 + i];
            acc[kn][0] = fmaf(xv, wv.x, acc[kn][0]);
            acc[kn][1] = fmaf(xv, wv.y, acc[kn][1]);
            acc[kn][2] = fmaf(xv, wv.z, acc[kn][2]);
            acc[kn][3] = fmaf(xv, wv.w, acc[kn][3]);
        }
    }
    const float4 bv  = *(const float4*)(bias + h * NO + o0);
    const float4 asv = *(const float4*)(attn_src + h * NO + o0);
    const float4 adv = *(const float4*)(attn_dst + h * NO + o0);
    const int bh = b * NH + h;
    float ssum[4], dsum[4];
    #pragma unroll
    for (int kn = 0; kn < 4; ++kn) {
        acc[kn][0] += bv.x; acc[kn][1] += bv.y;
        acc[kn][2] += bv.z; acc[kn][3] += bv.w;
        ssum[kn] = acc[kn][0]*asv.x + acc[kn][1]*asv.y + acc[kn][2]*asv.z + acc[kn][3]*asv.w;
        dsum[kn] = acc[kn][0]*adv.x + acc[kn][1]*adv.y + acc[kn][2]*adv.z + acc[kn][3]*adv.w;
    }
    #pragma unroll
    for (int oo = 0; oo < 4; ++oo) {
        half4v hv;
        hv[0] = (_Float16)acc[0][oo]; hv[1] = (_Float16)acc[1][oo];
        hv[2] = (_Float16)acc[2][oo]; hv[3] = (_Float16)acc[3][oo];
        *(half4v*)(projT + ((size_t)(bh * NO + o0 + oo)) * NN + n0b + nl0) = hv;
    }
    #pragma unroll
    for (int msk = 1; msk <= 4; msk <<= 1) {
        #pragma unroll
        for (int kn = 0; kn < 4; ++kn) {
            ssum[kn] += __shfl_xor(ssum[kn], msk, 64);
            dsum[kn] += __shfl_xor(dsum[kn], msk, 64);
        }
    }
    if (o4 == 0) {
        const float bx = beta[h];
        const float sp = fmaxf(bx, 0.f) + log1pf(__expf(-fabsf(bx)));
        #pragma unroll
        for (int kn = 0; kn < 4; ++kn) {
            const int n = n0b + nl0 + kn;
            src_s[bh * NN + n] = ssum[kn];
            dst_s[bh * NN + n] = dsum[kn];
            gp[bh * NN + n] = sp * prior[b * NN + n];
        }
    }
}

// ---------------- Kernel 2: two-pass flash attention, f16 MFMA ----------------
// grid (16 dtiles, 4 h, 8 b), 256 threads = 4 waves; wave owns 16 dst rows.
// Pass 1: exact masked row max (no shuffles needed later).
// Pass 2: p = exp(sc - rmax) directly into MFMA A-frags; zero barriers/shuffles
// in the inner loop; psum reduced once at the end.
#define VTP 1032   // vt row pitch in halfs (2064 B -> bank offset 4/row)

__global__ __launch_bounds__(256) void k_attn(
    const unsigned char* __restrict__ adjb,  // [N,N] bytes
    const _Float16* __restrict__ projT,      // [B,H,O,N]
    const float* __restrict__ src_s, const float* __restrict__ dst_s,
    const float* __restrict__ gp,
    float* __restrict__ out)                 // [B,N,H*O]
{
    __shared__ __align__(16) _Float16 vt[NO * VTP];   // 66 KB
    __shared__ __align__(16) float srcs[NN];
    __shared__ __align__(16) float gps[NN];
    __shared__ float pmax[64 * 4];
    const int t = threadIdx.x;
    const int lane = t & 63, wave = t >> 6;
    const int dtile = blockIdx.x, h = blockIdx.y, b = blockIdx.z;
    const int bh = b * NH + h;

    ((float4*)srcs)[t] = ((const float4*)(src_s + bh * NN))[t];
    ((float4*)gps)[t]  = ((const float4*)(gp + bh * NN))[t];
    const _Float16* ptrow = projT + (size_t)bh * NO * NN;
    #pragma unroll
    for (int k = 0; k < 16; ++k) {       // stage V^T: 32 rows x 1024 halfs
        const int e = t + k * 256;       // 4096 half8 slots
        const int o = e >> 7, sc8 = e & 127;
        *(half8*)&vt[o * VTP + sc8 * 8] =
            *(const half8*)(ptrow + (size_t)o * NN + sc8 * 8);
    }
    __syncthreads();

    // ---- Pass 1: masked row max. wave = s-quarter, lane = d row. ----
    {
        const int dl = lane, qt = wave;
        const int drow = dtile * 64 + dl;
        const float dv = dst_s[bh * NN + drow];
        const unsigned char* ar = adjb + (size_t)drow * NN + qt * 256;
        float mx = NEGINF;
        #pragma unroll 4
        for (int k = 0; k < 16; ++k) {
            const uint4 a4 = *(const uint4*)(ar + k * 16);
            const unsigned int wv[4] = {a4.x, a4.y, a4.z, a4.w};
            const int sb = qt * 256 + k * 16;
            #pragma unroll
            for (int w = 0; w < 4; ++w) {
                #pragma unroll
                for (int byi = 0; byi < 4; ++byi) {
                    const int s = sb + w * 4 + byi;   // srcs[s]: broadcast read
                    const float ts = dv + srcs[s];
                    const float sc = fmaxf(ts, 0.f) + 0.2f * fminf(ts, 0.f) + gps[s];
                    const bool on = (wv[w] >> (8 * byi)) & 1;
                    mx = fmaxf(mx, on ? sc : NEGINF);
                }
            }
        }
        pmax[dl * 4 + qt] = mx;
    }
    __syncthreads();

    // ---- Pass 2: exp + MFMA, no barriers/shuffles inside. ----
    const int m = lane & 15, quad = lane >> 4;
    const int d = dtile * 64 + wave * 16 + m;
    const float dreg = dst_s[bh * NN + d];
    const int pmb = (wave * 16 + m) * 4;
    const float rmx = fmaxf(fmaxf(pmax[pmb], pmax[pmb + 1]),
                            fmaxf(pmax[pmb + 2], pmax[pmb + 3]));
    const float rmc = (rmx > -1e29f) ? rmx : 0.f;   // fully-masked row -> 0
    const unsigned char* adjr = adjb + (size_t)d * NN;

    floatx4 acc0 = {0.f, 0.f, 0.f, 0.f}, acc1 = {0.f, 0.f, 0.f, 0.f};
    float psum = 0.f;
    uint2 apre = *(const uint2*)(adjr + quad * 8);

    for (int st = 0; st < 32; ++st) {
        const uint2 acur = apre;
        if (st < 31) apre = *(const uint2*)(adjr + (st + 1) * 32 + quad * 8);
        const int sg = st * 32 + quad * 8;
        float sv[8], gv[8];
        *(float4*)&sv[0] = *(const float4*)&srcs[sg];
        *(float4*)&sv[4] = *(const float4*)&srcs[sg + 4];
        *(float4*)&gv[0] = *(const float4*)&gps[sg];
        *(float4*)&gv[4] = *(const float4*)&gps[sg + 4];
        half8 af;
        #pragma unroll
        for (int j = 0; j < 8; ++j) {
            const unsigned int bit =
                ((j < 4 ? (acur.x >> (8 * j)) : (acur.y >> (8 * (j - 4)))) & 1u);
            const float ts = dreg + sv[j];
            const float lk = fmaxf(ts, 0.f) + 0.2f * fminf(ts, 0.f);
            const float sce = bit ? (lk + gv[j]) : NEGINF;   // exp(NEGINF-rmc)=0
            const float p = __expf(sce - rmc);               // p in [0,1]
            psum += p;
            af[j] = (_Float16)p;
        }
        const half8 b0 = *(const half8*)&vt[m * VTP + sg];
        const half8 b1 = *(const half8*)&vt[(16 + m) * VTP + sg];
        acc0 = __builtin_amdgcn_mfma_f32_16x16x32_f16(af, b0, acc0, 0, 0, 0);
        acc1 = __builtin_amdgcn_mfma_f32_16x16x32_f16(af, b1, acc1, 0, 0, 0);
    }
    psum += __shfl_xor(psum, 16, 64);
    psum += __shfl_xor(psum, 32, 64);

    #pragma unroll
    for (int r = 0; r < 4; ++r) {
        const int row = quad * 4 + r;
        const float lr = __shfl(psum, row, 64);
        const float inv = 1.f / fmaxf(lr, 1.1920929e-07f);
        float* go = out + ((size_t)(b * NN + dtile * 64 + wave * 16 + row)) * (NH * NO) + h * NO;
        go[m] = acc0[r] * inv;
        go[16 + m] = acc1[r] * inv;
    }
}

extern "C" void kernel_launch(void* const* d_in, const int* in_sizes, int n_in,
                              void* d_out, int out_size, void* d_ws, size_t ws_size,
                              hipStream_t stream) {
    (void)in_sizes; (void)n_in; (void)out_size; (void)ws_size;
    const float* x        = (const float*)d_in[0];
    const int*   adj      = (const int*)d_in[1];
    const float* prior    = (const float*)d_in[2];
    const float* beta     = (const float*)d_in[3];
    const float* weight   = (const float*)d_in[4];
    const float* attn_src = (const float*)d_in[5];
    const float* attn_dst = (const float*)d_in[6];
    const float* bias     = (const float*)d_in[7];
    float* out = (float*)d_out;

    _Float16* projT = (_Float16*)d_ws;                          // 2 MB
    float* src_s = (float*)((char*)d_ws + (1 << 21));           // 128 KB each
    float* dst_s = src_s + NB * NH * NN;
    float* gpb   = dst_s + NB * NH * NN;
    unsigned char* adjb = (unsigned char*)(gpb + NB * NH * NN); // 1 MB

    hipLaunchKernelGGL(k_pack, dim3(1024), dim3(256), 0, stream, adj, adjb);
    hipLaunchKernelGGL(k_proj, dim3(32, 8), dim3(256), 0, stream,
                       x, beta, weight, attn_src, attn_dst, bias, prior,
                       projT, src_s, dst_s, gpb);
    hipLaunchKernelGGL(k_attn, dim3(16, 4, 8), dim3(256), 0, stream,
                       adjb, projT, src_s, dst_s, gpb, out);
}